// Round 2
// baseline (872.590 us; speedup 1.0000x reference)
//
#include <hip/hip_runtime.h>
#include <cfloat>
#include <cmath>

// ---------------- types ----------------
typedef __attribute__((ext_vector_type(8))) short bf16x8;   // 8 bf16 (4 VGPRs) — MFMA A/B frag
typedef __attribute__((ext_vector_type(4))) float f32x4;    // MFMA C/D frag

__device__ __forceinline__ short f2bf(float f) {
    // fp32 -> bf16 round-to-nearest-even (inputs finite)
    unsigned u = __float_as_uint(f);
    u += 0x7fffu + ((u >> 16) & 1u);
    return (short)(u >> 16);
}

// ---------------- problem sizes ----------------
#define BATCH 64
#define KDIM  150528          // 3*224*224
#define NEMB  512
#define HIN_W 812             // 512 + 300
#define HID   400
#define ROWS  192             // B*C
#define RLEN  50176           // 224*224
#define NBINS 100
#define SEGS  8               // row segments for minmax/hist kernels
#define SEGF4 1568            // (RLEN/4)/SEGS

// GEMM tiling: grid (112 K-chunks x 8 N-tiles of 64) = 896 blocks -> ALL co-resident at 4/CU
#define NCHUNK 112
#define KC     1344
#define NTILE  64
#define BK     64
#define NSLAB  (KC / BK)      // 21
#define LDA    72             // 64 + 8 bf16 pad: 144 B row stride -> conflict-free b128 frag reads

// ---------------- ws layout (float offsets) ----------------
#define WS_HIN  0                             // 64*812 = 51968
#define WS_SEG  (WS_HIN + BATCH*HIN_W)        // per-seg minmax: mn[1536] | mx[1536]
#define WS_GB   (WS_SEG + 2*ROWS*SEGS)        // 192*100 uint global bins (zeroed by k_minmax)
#define WS_XBF  (WS_GB + ROWS*NBINS)          // bf16 x: 192*50176 shorts; byte off 296960 (16B aligned)
#define WS_PART (WS_XBF + ROWS*RLEN/2)        // 112*64*512 floats (~14.7 MB)

// ================= K1: per-(b,c,seg) min/max — atomic-free, + zero global bins =================
__global__ __launch_bounds__(256) void k_minmax(const float* __restrict__ x, float* __restrict__ ws) {
    int row = blockIdx.x >> 3, seg = blockIdx.x & 7;
    int tid = threadIdx.x, lane = tid & 63, wave = tid >> 6;
    // zero the global bins (19200 uints) in the first 75 blocks — completes before k_hist2 launches
    if (blockIdx.x < 75) ((unsigned*)(ws + WS_GB))[blockIdx.x * 256 + tid] = 0u;
    const float4* p = (const float4*)(x + (size_t)row * RLEN) + seg * SEGF4;
    float mn = FLT_MAX, mx = -FLT_MAX;
    for (int i = tid; i < SEGF4; i += 256) {
        float4 v = p[i];
        mn = fminf(mn, fminf(fminf(v.x, v.y), fminf(v.z, v.w)));
        mx = fmaxf(mx, fmaxf(fmaxf(v.x, v.y), fmaxf(v.z, v.w)));
    }
#pragma unroll
    for (int m = 1; m < 64; m <<= 1) {
        mn = fminf(mn, __shfl_xor(mn, m, 64));
        mx = fmaxf(mx, __shfl_xor(mx, m, 64));
    }
    __shared__ float smn[4], smx[4];
    if (lane == 0) { smn[wave] = mn; smx[wave] = mx; }
    __syncthreads();
    if (tid == 0) {
        mn = fminf(fminf(smn[0], smn[1]), fminf(smn[2], smn[3]));
        mx = fmaxf(fmaxf(smx[0], smx[1]), fmaxf(smx[2], smx[3]));
        ws[WS_SEG + blockIdx.x] = mn;                   // mn[row*8+seg]
        ws[WS_SEG + ROWS * SEGS + blockIdx.x] = mx;     // mx[row*8+seg]
    }
}

// ================= K2: histogram segment + bf16(x) emit — full-GPU =================
__global__ __launch_bounds__(256) void k_hist2(const float* __restrict__ x, float* __restrict__ ws) {
    int row = blockIdx.x >> 3, seg = blockIdx.x & 7;
    int tid = threadIdx.x, wave = tid >> 6;
    // reduce the 8 per-seg minmax slots for this row (redundant per-thread, L2-hot)
    float mn = ws[WS_SEG + row * 8], mx = ws[WS_SEG + ROWS * SEGS + row * 8];
#pragma unroll
    for (int i = 1; i < 8; ++i) {
        mn = fminf(mn, ws[WS_SEG + row * 8 + i]);
        mx = fmaxf(mx, ws[WS_SEG + ROWS * SEGS + row * 8 + i]);
    }
    float w = (mx > mn) ? (mx - mn) : 1.0f;
    __shared__ unsigned bins[4][NBINS];
    for (int i = tid; i < 4 * NBINS; i += 256) bins[i / NBINS][i % NBINS] = 0u;
    __syncthreads();
    const float4* p = (const float4*)(x + (size_t)row * RLEN) + seg * SEGF4;
    short* xrow = (short*)(ws + WS_XBF) + (size_t)row * RLEN + (size_t)seg * SEGF4 * 4;
    unsigned* mybins = bins[wave & 3];
    for (int i = tid; i < SEGF4; i += 256) {
        float4 v = p[i];
        float e[4] = {v.x, v.y, v.z, v.w};
#pragma unroll
        for (int j = 0; j < 4; ++j) {
            // exact reference fp32 op sequence: (x-mn)/width*100 -> floor -> int -> clip
            int idx = (int)floorf((e[j] - mn) / w * 100.0f);
            idx = idx < 0 ? 0 : (idx > 99 ? 99 : idx);
            atomicAdd(&mybins[idx], 1u);
        }
        *(short4*)&xrow[4 * i] = make_short4(f2bf(v.x), f2bf(v.y), f2bf(v.z), f2bf(v.w));
    }
    __syncthreads();
    if (tid < NBINS) {
        unsigned s = bins[0][tid] + bins[1][tid] + bins[2][tid] + bins[3][tid];
        unsigned* gb = (unsigned*)(ws + WS_GB);
        atomicAdd(&gb[row * NBINS + tid], s);
    }
}

// ================= K3: GEMM partials = A(bf16) @ base_W.T (split-K, LDS-staged bf16 MFMA) =================
// grid (112, 8), block 256 = 4 waves, all 896 blocks co-resident (3.5/CU at 4/CU residency).
__global__ __launch_bounds__(256, 4) void k_gemm(const float* __restrict__ ws_all, const float* __restrict__ W,
                                                 float* __restrict__ part) {
    __shared__ short sA[2][64 * LDA];
    __shared__ short sB[2][64 * LDA];

    int kc = blockIdx.x;
    int n0 = blockIdx.y * NTILE;
    int tid = threadIdx.x;
    int wave = tid >> 6, lane = tid & 63;
    int l15 = lane & 15, quad = lane >> 4;

    const short* Abf = (const short*)(ws_all + WS_XBF);

    // A loader: slab = 64 rows x 8 slots of 8 shorts (16B); 512 slots, 2 passes of 256.
    int arow[2], acol[2];
#pragma unroll
    for (int pp = 0; pp < 2; ++pp) { int slot = pp * 256 + tid; arow[pp] = slot >> 3; acol[pp] = slot & 7; }
    // B loader: slab = 64 rows x 16 float4; 1024 slots, 4 passes of 256.
    int brow[4], bf4[4];
#pragma unroll
    for (int pp = 0; pp < 4; ++pp) { int slot = pp * 256 + tid; brow[pp] = slot >> 4; bf4[pp] = slot & 15; }

    const short* Ab = Abf + (size_t)kc * KC;                           // + row*KDIM + s*BK + col*8
    const float* Bb = W + (size_t)n0 * KDIM + (size_t)kc * KC;         // + row*KDIM + s*BK + f4*4

    f32x4 acc[4];
#pragma unroll
    for (int mt = 0; mt < 4; ++mt) acc[mt] = (f32x4){0.f, 0.f, 0.f, 0.f};

    bf16x8 pfA[2];
    float4 pfB[4];
    // prologue: slab 0
#pragma unroll
    for (int pp = 0; pp < 2; ++pp)
        pfA[pp] = *(const bf16x8*)(Ab + (size_t)arow[pp] * KDIM + acol[pp] * 8);
#pragma unroll
    for (int pp = 0; pp < 4; ++pp)
        pfB[pp] = *(const float4*)(Bb + (size_t)brow[pp] * KDIM + bf4[pp] * 4);
#pragma unroll
    for (int pp = 0; pp < 2; ++pp)
        *(bf16x8*)&sA[0][arow[pp] * LDA + acol[pp] * 8] = pfA[pp];
#pragma unroll
    for (int pp = 0; pp < 4; ++pp)
        *(short4*)&sB[0][brow[pp] * LDA + bf4[pp] * 4] =
            make_short4(f2bf(pfB[pp].x), f2bf(pfB[pp].y), f2bf(pfB[pp].z), f2bf(pfB[pp].w));
    __syncthreads();

    for (int s = 0; s < NSLAB; ++s) {
        int buf = s & 1;
        if (s + 1 < NSLAB) {   // issue next-slab loads: a full slab of compute hides them
            const short* An = Ab + (s + 1) * BK;
            const float* Bn = Bb + (s + 1) * BK;
#pragma unroll
            for (int pp = 0; pp < 2; ++pp)
                pfA[pp] = *(const bf16x8*)(An + (size_t)arow[pp] * KDIM + acol[pp] * 8);
#pragma unroll
            for (int pp = 0; pp < 4; ++pp)
                pfB[pp] = *(const float4*)(Bn + (size_t)brow[pp] * KDIM + bf4[pp] * 4);
        }
#pragma unroll
        for (int ks = 0; ks < 2; ++ks) {
            bf16x8 bf = *(const bf16x8*)&sB[buf][(wave * 16 + l15) * LDA + ks * 32 + quad * 8];
#pragma unroll
            for (int mt = 0; mt < 4; ++mt) {
                bf16x8 af = *(const bf16x8*)&sA[buf][(mt * 16 + l15) * LDA + ks * 32 + quad * 8];
                acc[mt] = __builtin_amdgcn_mfma_f32_16x16x32_bf16(af, bf, acc[mt], 0, 0, 0);
            }
        }
        if (s + 1 < NSLAB) {
            int nbuf = buf ^ 1;
#pragma unroll
            for (int pp = 0; pp < 2; ++pp)
                *(bf16x8*)&sA[nbuf][arow[pp] * LDA + acol[pp] * 8] = pfA[pp];
#pragma unroll
            for (int pp = 0; pp < 4; ++pp)
                *(short4*)&sB[nbuf][brow[pp] * LDA + bf4[pp] * 4] =
                    make_short4(f2bf(pfB[pp].x), f2bf(pfB[pp].y), f2bf(pfB[pp].z), f2bf(pfB[pp].w));
        }
        __syncthreads();
    }

    // C/D layout: col = lane&15 (n), row = quad*4 + reg (m)   [rounds 1-3 validated]
    float* pb = part + (size_t)kc * (BATCH * NEMB);
#pragma unroll
    for (int mt = 0; mt < 4; ++mt) {
        int n = n0 + wave * 16 + l15;
#pragma unroll
        for (int r = 0; r < 4; ++r) {
            int m = mt * 16 + quad * 4 + r;
            pb[m * NEMB + n] = acc[mt][r];
        }
    }
}

// ================= K4: reduce split-K partials + bias -> h_in[:, :512]; blocks 0-74 also bins->float =================
__global__ __launch_bounds__(256) void k_reduce(const float* __restrict__ part, const float* __restrict__ bias,
                                                float* __restrict__ ws) {
    __shared__ float sm[256];
    int tid = threadIdx.x;
    // fold former k_binf: copy global bins (uint) into h_in hist columns
    if (blockIdx.x < 75) {
        int i = blockIdx.x * 256 + tid;                // 19200 exact
        unsigned gv = ((const unsigned*)(ws + WS_GB))[i];
        int row = i / NBINS, bin = i - row * NBINS;
        int b = row / 3, c = row - b * 3;
        ws[WS_HIN + b * HIN_W + NEMB + c * NBINS + bin] = (float)gv;
    }
    int o = blockIdx.x * 32 + (tid & 31);     // 32768 outputs
    int slice = tid >> 5;                     // 0..7; 112/8 = 14 iters exact
    float s = 0.f;
    for (int c = slice; c < NCHUNK; c += 8) s += part[(size_t)c * (BATCH * NEMB) + o];
    sm[tid] = s;
    __syncthreads();
    if (tid < 32) {
        float t = sm[tid];
#pragma unroll
        for (int sl = 1; sl < 8; ++sl) t += sm[sl * 32 + tid];
        int m = o >> 9, n = o & 511;
        ws[WS_HIN + m * HIN_W + n] = t + bias[n];
    }
}

// ================= K5: fused MLP tail — one block per sample, h & t in LDS =================
// layer1 (relu(hin@hW.T+hb)) -> heads layer-1 -> heads layer-2 + relu + softmax -> d_out
__global__ __launch_bounds__(1024) void k_tail(const float* __restrict__ hin,
                                               const float* __restrict__ hW, const float* __restrict__ hb,
                                               const float* __restrict__ stW1, const float* __restrict__ stb1,
                                               const float* __restrict__ stW2, const float* __restrict__ stb2,
                                               const float* __restrict__ ageW1, const float* __restrict__ ageb1,
                                               const float* __restrict__ ageW2, const float* __restrict__ ageb2,
                                               const float* __restrict__ genW1, const float* __restrict__ genb1,
                                               const float* __restrict__ genW2, const float* __restrict__ genb2,
                                               float* __restrict__ out) {
    int b = blockIdx.x;                       // 64 samples
    int tid = threadIdx.x, lane = tid & 63, wave = tid >> 6;   // 16 waves
    __shared__ float sx[HIN_W];               // 812
    __shared__ float sh[HID];                 // 400
    __shared__ float st[1400];
    __shared__ float lg[16];

    for (int i = tid; i < HIN_W; i += 1024) sx[i] = hin[b * HIN_W + i];
    __syncthreads();

    // layer1: 400 outputs, one wave per output (lane-strided dot over 812)
    for (int j = wave; j < HID; j += 16) {
        const float* wr = hW + (size_t)j * HIN_W;
        float s = 0.f;
        for (int k = lane; k < HIN_W; k += 64) s += sx[k] * wr[k];
#pragma unroll
        for (int m = 1; m < 64; m <<= 1) s += __shfl_xor(s, m, 64);
        if (lane == 0) sh[j] = fmaxf(s + hb[j], 0.f);
    }
    __syncthreads();

    // heads layer-1: 1400 outputs (st600 | age400 | gen400), one wave per output
    for (int o = wave; o < 1400; o += 16) {
        const float* wr; float bias;
        if (o < 600)       { wr = stW1  + (size_t)o * 400;          bias = stb1[o]; }
        else if (o < 1000) { wr = ageW1 + (size_t)(o - 600) * 400;  bias = ageb1[o - 600]; }
        else               { wr = genW1 + (size_t)(o - 1000) * 400; bias = genb1[o - 1000]; }
        float s = 0.f;
        for (int k = lane; k < 400; k += 64) s += sh[k] * wr[k];
#pragma unroll
        for (int m = 1; m < 64; m <<= 1) s += __shfl_xor(s, m, 64);
        if (lane == 0) st[o] = fmaxf(s + bias, 0.f);
    }
    __syncthreads();

    // heads layer-2 + relu: 16 outputs x 16 lanes (threads 0..255)
    if (tid < 256) {
        int o = tid >> 4, sub = tid & 15;
        const float* wr; const float* tb; float bias; int Klen;
        if (o < 10)      { wr = stW2  + o * 600;        tb = st;        bias = stb2[o];       Klen = 600; }
        else if (o < 14) { wr = ageW2 + (o - 10) * 400; tb = st + 600;  bias = ageb2[o - 10]; Klen = 400; }
        else             { wr = genW2 + (o - 14) * 400; tb = st + 1000; bias = genb2[o - 14]; Klen = 400; }
        float s = 0.f;
        for (int k = sub; k < Klen; k += 16) s += tb[k] * wr[k];
#pragma unroll
        for (int m = 1; m < 16; m <<= 1) s += __shfl_xor(s, m, 64);   // xor within aligned 16-lane group
        if (sub == 0) lg[o] = fmaxf(s + bias, 0.f);
    }
    __syncthreads();

    if (tid == 0) {         // softmax st -> out[b*10]
        float mx = lg[0];
        for (int i = 1; i < 10; ++i) mx = fmaxf(mx, lg[i]);
        float e[10], sum = 0.f;
        for (int i = 0; i < 10; ++i) { e[i] = expf(lg[i] - mx); sum += e[i]; }
        for (int i = 0; i < 10; ++i) out[b * 10 + i] = e[i] / sum;
    } else if (tid == 1) {  // softmax age -> out[640 + b*4]
        float mx = lg[10];
        for (int i = 1; i < 4; ++i) mx = fmaxf(mx, lg[10 + i]);
        float e[4], sum = 0.f;
        for (int i = 0; i < 4; ++i) { e[i] = expf(lg[10 + i] - mx); sum += e[i]; }
        for (int i = 0; i < 4; ++i) out[640 + b * 4 + i] = e[i] / sum;
    } else if (tid == 2) {  // softmax gender -> out[896 + b*2]
        float mx = fmaxf(lg[14], lg[15]);
        float e0 = expf(lg[14] - mx), e1 = expf(lg[15] - mx);
        float sum = e0 + e1;
        out[896 + b * 2 + 0] = e0 / sum;
        out[896 + b * 2 + 1] = e1 / sum;
    }
}

// ================= launch =================
extern "C" void kernel_launch(void* const* d_in, const int* in_sizes, int n_in,
                              void* d_out, int out_size, void* d_ws, size_t ws_size,
                              hipStream_t stream) {
    (void)in_sizes; (void)n_in; (void)out_size; (void)ws_size;
    const float* x      = (const float*)d_in[0];
    const float* base_W = (const float*)d_in[1];
    const float* base_b = (const float*)d_in[2];
    const float* hW     = (const float*)d_in[3];
    const float* hb     = (const float*)d_in[4];
    const float* stW1   = (const float*)d_in[5];
    const float* stb1   = (const float*)d_in[6];
    const float* stW2   = (const float*)d_in[7];
    const float* stb2   = (const float*)d_in[8];
    const float* ageW1  = (const float*)d_in[9];
    const float* ageb1  = (const float*)d_in[10];
    const float* ageW2  = (const float*)d_in[11];
    const float* ageb2  = (const float*)d_in[12];
    const float* genW1  = (const float*)d_in[13];
    const float* genb1  = (const float*)d_in[14];
    const float* genW2  = (const float*)d_in[15];
    const float* genb2  = (const float*)d_in[16];
    float* ws  = (float*)d_ws;
    float* out = (float*)d_out;

    k_minmax<<<ROWS * SEGS, 256, 0, stream>>>(x, ws);
    k_hist2 <<<ROWS * SEGS, 256, 0, stream>>>(x, ws);
    k_gemm  <<<dim3(NCHUNK, NEMB / NTILE), 256, 0, stream>>>(ws, base_W, ws + WS_PART);
    k_reduce<<<(BATCH * NEMB) / 32, 256, 0, stream>>>(ws + WS_PART, base_b, ws);
    k_tail  <<<BATCH, 1024, 0, stream>>>(ws + WS_HIN, hW, hb,
                                         stW1, stb1, stW2, stb2,
                                         ageW1, ageb1, ageW2, ageb2,
                                         genW1, genb1, genW2, genb2, out);
}

// Round 3
// 554.175 us; speedup vs baseline: 1.5746x; 1.5746x over previous
//
#include <hip/hip_runtime.h>
#include <cfloat>
#include <cmath>

// ---------------- types ----------------
typedef __attribute__((ext_vector_type(8))) short bf16x8;   // 8 bf16 (4 VGPRs) — MFMA A/B frag
typedef __attribute__((ext_vector_type(4))) float f32x4;    // MFMA C/D frag

__device__ __forceinline__ short f2bf(float f) {
    // fp32 -> bf16 round-to-nearest-even (inputs finite)
    unsigned u = __float_as_uint(f);
    u += 0x7fffu + ((u >> 16) & 1u);
    return (short)(u >> 16);
}

// ---------------- problem sizes ----------------
#define BATCH 64
#define KDIM  150528          // 3*224*224
#define NEMB  512
#define HIN_W 812             // 512 + 300
#define HID   400
#define ROWS  192             // B*C
#define RLEN  50176           // 224*224
#define NBINS 100
#define SEGS  8               // row segments for minmax/hist kernels
#define SEGF4 1568            // (RLEN/4)/SEGS

// GEMM tiling: grid (112 K-chunks x 8 N-tiles of 64) = 896 blocks -> ALL co-resident at 4/CU
#define NCHUNK 112
#define KC     1344
#define NTILE  64
#define BK     64
#define NSLAB  (KC / BK)      // 21
#define LDA    72             // 64 + 8 bf16 pad: 144 B row stride -> conflict-free b128 frag reads

// ---------------- ws layout (float offsets) ----------------
#define WS_HIN  0                             // 64*812 = 51968
#define WS_H    (WS_HIN + BATCH*HIN_W)        // 64*400 = 25600
#define WS_T    (WS_H + BATCH*HID)            // 64*1400 = 89600
#define WS_SEG  (WS_T + BATCH*1400)           // per-seg minmax: mn[1536] | mx[1536]
#define WS_GB   (WS_SEG + 2*ROWS*SEGS)        // 192*100 uint global bins (zeroed by k_minmax)
#define WS_XBF  (WS_GB + ROWS*NBINS)          // bf16 x: 192*50176 shorts (16B-aligned byte offset)
#define WS_PART (WS_XBF + ROWS*RLEN/2)        // 112*64*512 floats (~14.7 MB)

// ================= K1: per-(b,c,seg) min/max + bf16 emit — atomic-free, + zero global bins =================
// bf16(x) emit lives here (doesn't depend on min/max) to keep VALU+stores out of the atomic hist kernel.
__global__ __launch_bounds__(256) void k_minmax(const float* __restrict__ x, float* __restrict__ ws) {
    int row = blockIdx.x >> 3, seg = blockIdx.x & 7;
    int tid = threadIdx.x, lane = tid & 63, wave = tid >> 6;
    // zero the global bins (19200 uints) in the first 75 blocks — done before k_hist2 launches
    if (blockIdx.x < 75) ((unsigned*)(ws + WS_GB))[blockIdx.x * 256 + tid] = 0u;
    const float4* p = (const float4*)(x + (size_t)row * RLEN) + seg * SEGF4;
    short* xrow = (short*)(ws + WS_XBF) + (size_t)row * RLEN + (size_t)seg * SEGF4 * 4;
    float mn = FLT_MAX, mx = -FLT_MAX;
    for (int i = tid; i < SEGF4; i += 256) {
        float4 v = p[i];
        mn = fminf(mn, fminf(fminf(v.x, v.y), fminf(v.z, v.w)));
        mx = fmaxf(mx, fmaxf(fmaxf(v.x, v.y), fmaxf(v.z, v.w)));
        *(short4*)&xrow[4 * i] = make_short4(f2bf(v.x), f2bf(v.y), f2bf(v.z), f2bf(v.w));
    }
#pragma unroll
    for (int m = 1; m < 64; m <<= 1) {
        mn = fminf(mn, __shfl_xor(mn, m, 64));
        mx = fmaxf(mx, __shfl_xor(mx, m, 64));
    }
    __shared__ float smn[4], smx[4];
    if (lane == 0) { smn[wave] = mn; smx[wave] = mx; }
    __syncthreads();
    if (tid == 0) {
        mn = fminf(fminf(smn[0], smn[1]), fminf(smn[2], smn[3]));
        mx = fmaxf(fmaxf(smx[0], smx[1]), fmaxf(smx[2], smx[3]));
        ws[WS_SEG + blockIdx.x] = mn;                   // mn[row*8+seg]
        ws[WS_SEG + ROWS * SEGS + blockIdx.x] = mx;     // mx[row*8+seg]
    }
}

// ================= K2: histogram segment — full-GPU, x re-read is L3-hot =================
__global__ __launch_bounds__(256) void k_hist2(const float* __restrict__ x, float* __restrict__ ws) {
    int row = blockIdx.x >> 3, seg = blockIdx.x & 7;
    int tid = threadIdx.x, wave = tid >> 6;
    // reduce the 8 per-seg minmax slots for this row (redundant per-thread, L2-hot)
    float mn = ws[WS_SEG + row * 8], mx = ws[WS_SEG + ROWS * SEGS + row * 8];
#pragma unroll
    for (int i = 1; i < 8; ++i) {
        mn = fminf(mn, ws[WS_SEG + row * 8 + i]);
        mx = fmaxf(mx, ws[WS_SEG + ROWS * SEGS + row * 8 + i]);
    }
    float w = (mx > mn) ? (mx - mn) : 1.0f;
    __shared__ unsigned bins[4][NBINS];
    for (int i = tid; i < 4 * NBINS; i += 256) bins[i / NBINS][i % NBINS] = 0u;
    __syncthreads();
    const float4* p = (const float4*)(x + (size_t)row * RLEN) + seg * SEGF4;
    unsigned* mybins = bins[wave & 3];
    for (int i = tid; i < SEGF4; i += 256) {
        float4 v = p[i];
        float e[4] = {v.x, v.y, v.z, v.w};
#pragma unroll
        for (int j = 0; j < 4; ++j) {
            // exact reference fp32 op sequence: (x-mn)/width*100 -> floor -> int -> clip
            int idx = (int)floorf((e[j] - mn) / w * 100.0f);
            idx = idx < 0 ? 0 : (idx > 99 ? 99 : idx);
            atomicAdd(&mybins[idx], 1u);
        }
    }
    __syncthreads();
    if (tid < NBINS) {
        unsigned s = bins[0][tid] + bins[1][tid] + bins[2][tid] + bins[3][tid];
        unsigned* gb = (unsigned*)(ws + WS_GB);
        atomicAdd(&gb[row * NBINS + tid], s);
    }
}

// ================= K3: GEMM partials = A(bf16) @ base_W.T (split-K, LDS-staged bf16 MFMA) =================
// grid (112, 8), block 256 = 4 waves, all 896 blocks co-resident (3.5/CU at 4/CU residency).
__global__ __launch_bounds__(256, 4) void k_gemm(const float* __restrict__ ws_all, const float* __restrict__ W,
                                                 float* __restrict__ part) {
    __shared__ short sA[2][64 * LDA];
    __shared__ short sB[2][64 * LDA];

    int kc = blockIdx.x;
    int n0 = blockIdx.y * NTILE;
    int tid = threadIdx.x;
    int wave = tid >> 6, lane = tid & 63;
    int l15 = lane & 15, quad = lane >> 4;

    const short* Abf = (const short*)(ws_all + WS_XBF);

    // A loader: slab = 64 rows x 8 slots of 8 shorts (16B); 512 slots, 2 passes of 256.
    int arow[2], acol[2];
#pragma unroll
    for (int pp = 0; pp < 2; ++pp) { int slot = pp * 256 + tid; arow[pp] = slot >> 3; acol[pp] = slot & 7; }
    // B loader: slab = 64 rows x 16 float4; 1024 slots, 4 passes of 256.
    int brow[4], bf4[4];
#pragma unroll
    for (int pp = 0; pp < 4; ++pp) { int slot = pp * 256 + tid; brow[pp] = slot >> 4; bf4[pp] = slot & 15; }

    const short* Ab = Abf + (size_t)kc * KC;                           // + row*KDIM + s*BK + col*8
    const float* Bb = W + (size_t)n0 * KDIM + (size_t)kc * KC;         // + row*KDIM + s*BK + f4*4

    f32x4 acc[4];
#pragma unroll
    for (int mt = 0; mt < 4; ++mt) acc[mt] = (f32x4){0.f, 0.f, 0.f, 0.f};

    bf16x8 pfA[2];
    float4 pfB[4];
    // prologue: slab 0
#pragma unroll
    for (int pp = 0; pp < 2; ++pp)
        pfA[pp] = *(const bf16x8*)(Ab + (size_t)arow[pp] * KDIM + acol[pp] * 8);
#pragma unroll
    for (int pp = 0; pp < 4; ++pp)
        pfB[pp] = *(const float4*)(Bb + (size_t)brow[pp] * KDIM + bf4[pp] * 4);
#pragma unroll
    for (int pp = 0; pp < 2; ++pp)
        *(bf16x8*)&sA[0][arow[pp] * LDA + acol[pp] * 8] = pfA[pp];
#pragma unroll
    for (int pp = 0; pp < 4; ++pp)
        *(short4*)&sB[0][brow[pp] * LDA + bf4[pp] * 4] =
            make_short4(f2bf(pfB[pp].x), f2bf(pfB[pp].y), f2bf(pfB[pp].z), f2bf(pfB[pp].w));
    __syncthreads();

    for (int s = 0; s < NSLAB; ++s) {
        int buf = s & 1;
        if (s + 1 < NSLAB) {   // issue next-slab loads: a full slab of compute hides them
            const short* An = Ab + (s + 1) * BK;
            const float* Bn = Bb + (s + 1) * BK;
#pragma unroll
            for (int pp = 0; pp < 2; ++pp)
                pfA[pp] = *(const bf16x8*)(An + (size_t)arow[pp] * KDIM + acol[pp] * 8);
#pragma unroll
            for (int pp = 0; pp < 4; ++pp)
                pfB[pp] = *(const float4*)(Bn + (size_t)brow[pp] * KDIM + bf4[pp] * 4);
        }
#pragma unroll
        for (int ks = 0; ks < 2; ++ks) {
            bf16x8 bf = *(const bf16x8*)&sB[buf][(wave * 16 + l15) * LDA + ks * 32 + quad * 8];
#pragma unroll
            for (int mt = 0; mt < 4; ++mt) {
                bf16x8 af = *(const bf16x8*)&sA[buf][(mt * 16 + l15) * LDA + ks * 32 + quad * 8];
                acc[mt] = __builtin_amdgcn_mfma_f32_16x16x32_bf16(af, bf, acc[mt], 0, 0, 0);
            }
        }
        if (s + 1 < NSLAB) {
            int nbuf = buf ^ 1;
#pragma unroll
            for (int pp = 0; pp < 2; ++pp)
                *(bf16x8*)&sA[nbuf][arow[pp] * LDA + acol[pp] * 8] = pfA[pp];
#pragma unroll
            for (int pp = 0; pp < 4; ++pp)
                *(short4*)&sB[nbuf][brow[pp] * LDA + bf4[pp] * 4] =
                    make_short4(f2bf(pfB[pp].x), f2bf(pfB[pp].y), f2bf(pfB[pp].z), f2bf(pfB[pp].w));
        }
        __syncthreads();
    }

    // C/D layout: col = lane&15 (n), row = quad*4 + reg (m)   [rounds 1-3 validated]
    float* pb = part + (size_t)kc * (BATCH * NEMB);
#pragma unroll
    for (int mt = 0; mt < 4; ++mt) {
        int n = n0 + wave * 16 + l15;
#pragma unroll
        for (int r = 0; r < 4; ++r) {
            int m = mt * 16 + quad * 4 + r;
            pb[m * NEMB + n] = acc[mt][r];
        }
    }
}

// ================= K4: reduce split-K partials + bias -> h_in[:, :512]; blocks 0-74 also bins->float =================
__global__ __launch_bounds__(256) void k_reduce(const float* __restrict__ part, const float* __restrict__ bias,
                                                float* __restrict__ ws) {
    __shared__ float sm[256];
    int tid = threadIdx.x;
    // fold former k_binf: copy global bins (uint) into h_in hist columns
    if (blockIdx.x < 75) {
        int i = blockIdx.x * 256 + tid;                // 19200 exact
        unsigned gv = ((const unsigned*)(ws + WS_GB))[i];
        int row = i / NBINS, bin = i - row * NBINS;
        int b = row / 3, c = row - b * 3;
        ws[WS_HIN + b * HIN_W + NEMB + c * NBINS + bin] = (float)gv;
    }
    int o = blockIdx.x * 32 + (tid & 31);     // 32768 outputs
    int slice = tid >> 5;                     // 0..7; 112/8 = 14 iters exact
    float s = 0.f;
    for (int c = slice; c < NCHUNK; c += 8) s += part[(size_t)c * (BATCH * NEMB) + o];
    sm[tid] = s;
    __syncthreads();
    if (tid < 32) {
        float t = sm[tid];
#pragma unroll
        for (int sl = 1; sl < 8; ++sl) t += sm[sl * 32 + tid];
        int m = o >> 9, n = o & 511;
        ws[WS_HIN + m * HIN_W + n] = t + bias[n];
    }
}

// ================= K5: h = relu(h_in @ hW.T + hb) — one wave per output =================
__global__ __launch_bounds__(256) void k_layer1(const float* __restrict__ hin, const float* __restrict__ hW,
                                                const float* __restrict__ hb, float* __restrict__ h) {
    int wave = threadIdx.x >> 6, lane = threadIdx.x & 63;
    int gid = blockIdx.x * 4 + wave;           // 25600 outputs
    int b = gid / HID, j = gid - b * HID;
    const float* hr = hin + b * HIN_W;
    const float* wr = hW + j * HIN_W;
    float s = 0.f;
    for (int k = lane; k < HIN_W; k += 64) s += hr[k] * wr[k];
#pragma unroll
    for (int m = 1; m < 64; m <<= 1) s += __shfl_xor(s, m, 64);
    if (lane == 0) h[b * HID + j] = fmaxf(s + hb[j], 0.f);
}

// ================= K6: heads layer-1 (st600 | age400 | gen400 concat) =================
__global__ __launch_bounds__(256) void k_heads1(const float* __restrict__ h,
                                                const float* __restrict__ stW1, const float* __restrict__ stb1,
                                                const float* __restrict__ ageW1, const float* __restrict__ ageb1,
                                                const float* __restrict__ genW1, const float* __restrict__ genb1,
                                                float* __restrict__ t) {
    int wave = threadIdx.x >> 6, lane = threadIdx.x & 63;
    int gid = blockIdx.x * 4 + wave;           // 89600 outputs
    int b = gid / 1400, o = gid - b * 1400;
    const float* wr; float bias;
    if (o < 600)       { wr = stW1  + (size_t)o * 400;          bias = stb1[o]; }
    else if (o < 1000) { wr = ageW1 + (size_t)(o - 600) * 400;  bias = ageb1[o - 600]; }
    else               { wr = genW1 + (size_t)(o - 1000) * 400; bias = genb1[o - 1000]; }
    const float* hr = h + b * HID;
    float s = 0.f;
    for (int k = lane; k < 400; k += 64) s += hr[k] * wr[k];
#pragma unroll
    for (int m = 1; m < 64; m <<= 1) s += __shfl_xor(s, m, 64);
    if (lane == 0) t[b * 1400 + o] = fmaxf(s + bias, 0.f);
}

// ================= K7: heads layer-2 + relu + softmax -> d_out =================
// 64 blocks x 256: 16 outputs x 16 lanes each.
__global__ __launch_bounds__(256) void k_heads2(const float* __restrict__ t,
                                                const float* __restrict__ stW2, const float* __restrict__ stb2,
                                                const float* __restrict__ ageW2, const float* __restrict__ ageb2,
                                                const float* __restrict__ genW2, const float* __restrict__ genb2,
                                                float* __restrict__ out) {
    int b = blockIdx.x;
    int tid = threadIdx.x;
    int o = tid >> 4, sub = tid & 15;          // 16 outputs x 16 lanes
    const float* tr = t + b * 1400;
    const float* wr; const float* tb; float bias; int Klen;
    if (o < 10)      { wr = stW2  + o * 600;        tb = tr;        bias = stb2[o];       Klen = 600; }
    else if (o < 14) { wr = ageW2 + (o - 10) * 400; tb = tr + 600;  bias = ageb2[o - 10]; Klen = 400; }
    else             { wr = genW2 + (o - 14) * 400; tb = tr + 1000; bias = genb2[o - 14]; Klen = 400; }
    float s = 0.f;
    for (int k = sub; k < Klen; k += 16) s += tb[k] * wr[k];
#pragma unroll
    for (int m = 1; m < 16; m <<= 1) s += __shfl_xor(s, m, 64);   // xor within aligned 16-lane group
    __shared__ float lg[16];
    if (sub == 0) lg[o] = fmaxf(s + bias, 0.f);   // relu(logits)
    __syncthreads();
    if (tid == 0) {         // softmax st -> out[b*10]
        float mx = lg[0];
        for (int i = 1; i < 10; ++i) mx = fmaxf(mx, lg[i]);
        float e[10], sum = 0.f;
        for (int i = 0; i < 10; ++i) { e[i] = expf(lg[i] - mx); sum += e[i]; }
        for (int i = 0; i < 10; ++i) out[b * 10 + i] = e[i] / sum;
    } else if (tid == 1) {  // softmax age -> out[640 + b*4]
        float mx = lg[10];
        for (int i = 1; i < 4; ++i) mx = fmaxf(mx, lg[10 + i]);
        float e[4], sum = 0.f;
        for (int i = 0; i < 4; ++i) { e[i] = expf(lg[10 + i] - mx); sum += e[i]; }
        for (int i = 0; i < 4; ++i) out[640 + b * 4 + i] = e[i] / sum;
    } else if (tid == 2) {  // softmax gender -> out[896 + b*2]
        float mx = fmaxf(lg[14], lg[15]);
        float e0 = expf(lg[14] - mx), e1 = expf(lg[15] - mx);
        float sum = e0 + e1;
        out[896 + b * 2 + 0] = e0 / sum;
        out[896 + b * 2 + 1] = e1 / sum;
    }
}

// ================= launch =================
extern "C" void kernel_launch(void* const* d_in, const int* in_sizes, int n_in,
                              void* d_out, int out_size, void* d_ws, size_t ws_size,
                              hipStream_t stream) {
    (void)in_sizes; (void)n_in; (void)out_size; (void)ws_size;
    const float* x      = (const float*)d_in[0];
    const float* base_W = (const float*)d_in[1];
    const float* base_b = (const float*)d_in[2];
    const float* hW     = (const float*)d_in[3];
    const float* hb     = (const float*)d_in[4];
    const float* stW1   = (const float*)d_in[5];
    const float* stb1   = (const float*)d_in[6];
    const float* stW2   = (const float*)d_in[7];
    const float* stb2   = (const float*)d_in[8];
    const float* ageW1  = (const float*)d_in[9];
    const float* ageb1  = (const float*)d_in[10];
    const float* ageW2  = (const float*)d_in[11];
    const float* ageb2  = (const float*)d_in[12];
    const float* genW1  = (const float*)d_in[13];
    const float* genb1  = (const float*)d_in[14];
    const float* genW2  = (const float*)d_in[15];
    const float* genb2  = (const float*)d_in[16];
    float* ws  = (float*)d_ws;
    float* out = (float*)d_out;

    k_minmax<<<ROWS * SEGS, 256, 0, stream>>>(x, ws);
    k_hist2 <<<ROWS * SEGS, 256, 0, stream>>>(x, ws);
    k_gemm  <<<dim3(NCHUNK, NEMB / NTILE), 256, 0, stream>>>(ws, base_W, ws + WS_PART);
    k_reduce<<<(BATCH * NEMB) / 32, 256, 0, stream>>>(ws + WS_PART, base_b, ws);
    k_layer1<<<(BATCH * HID) / 4, 256, 0, stream>>>(ws + WS_HIN, hW, hb, ws + WS_H);
    k_heads1<<<(BATCH * 1400) / 4, 256, 0, stream>>>(ws + WS_H, stW1, stb1, ageW1, ageb1, genW1, genb1, ws + WS_T);
    k_heads2<<<BATCH, 256, 0, stream>>>(ws + WS_T, stW2, stb2, ageW2, ageb2, genW2, genb2, out);
}